// Round 1
// baseline (793.274 us; speedup 1.0000x reference)
//
#include <hip/hip_runtime.h>
#include <math.h>

#define B_  1024
#define S_  256
#define H_  512
#define E_  64
#define R_  32
#define L_  9
#define EPS_ 1e-6f
#define TB  16   // b-tile for MLP kernel

// ---------------------------------------------------------------------------
// Kernel 1: fused 2-layer MLP for the 4 live modules (m=0 -> e[0], m=1..3 -> r[0..2])
// h = tanh(x @ W1 + b1); out = h @ W2 + b2
// grid (B/TB, 4), block 256
// ---------------------------------------------------------------------------
__global__ __launch_bounds__(256) void mlp_kernel(
    const float* __restrict__ x,     // [B,S]
    const float* __restrict__ eW1, const float* __restrict__ eb1,
    const float* __restrict__ eW2, const float* __restrict__ eb2,
    const float* __restrict__ rW1, const float* __restrict__ rb1,
    const float* __restrict__ rW2, const float* __restrict__ rb2,
    float* __restrict__ e0_out,      // [B,E]
    float* __restrict__ r_out)       // [3,B,R]
{
    __shared__ float xs[TB][S_];     // 16 KB
    __shared__ float hs[TB][H_];     // 32 KB
    const int t  = threadIdx.x;
    const int b0 = blockIdx.x * TB;
    const int m  = blockIdx.y;       // 0 = e0, 1..3 = r0..r2

    // load X tile (coalesced)
    #pragma unroll
    for (int i = 0; i < TB; ++i)
        xs[i][t] = x[(size_t)(b0 + i) * S_ + t];
    __syncthreads();

    const float* W1 = (m == 0) ? eW1 : (rW1 + (size_t)(m - 1) * S_ * H_);
    const float* b1 = (m == 0) ? eb1 : (rb1 + (size_t)(m - 1) * H_);

    // layer 1: thread owns columns j=t and j=t+256 for all TB rows
    float acc0[TB], acc1[TB];
    #pragma unroll
    for (int bb = 0; bb < TB; ++bb) { acc0[bb] = 0.0f; acc1[bb] = 0.0f; }

    for (int s = 0; s < S_; ++s) {
        float w0 = W1[(size_t)s * H_ + t];
        float w1 = W1[(size_t)s * H_ + t + 256];
        #pragma unroll
        for (int bb = 0; bb < TB; ++bb) {
            float xv = xs[bb][s];
            acc0[bb] = fmaf(xv, w0, acc0[bb]);
            acc1[bb] = fmaf(xv, w1, acc1[bb]);
        }
    }
    float bias0 = b1[t], bias1 = b1[t + 256];
    #pragma unroll
    for (int bb = 0; bb < TB; ++bb) {
        hs[bb][t]       = tanhf(acc0[bb] + bias0);
        hs[bb][t + 256] = tanhf(acc1[bb] + bias1);
    }
    __syncthreads();

    // layer 2
    if (m == 0) {
        const float* W2 = eW2;
        const float* b2 = eb2;
        int o  = t & 63;
        int bq = t >> 6;                     // 0..3
        #pragma unroll
        for (int i = 0; i < TB / 4; ++i) {
            int bb = bq + i * 4;
            float acc = b2[o];
            for (int j = 0; j < H_; ++j)
                acc = fmaf(hs[bb][j], W2[(size_t)j * E_ + o], acc);
            e0_out[(size_t)(b0 + bb) * E_ + o] = acc;
        }
    } else {
        const float* W2 = rW2 + (size_t)(m - 1) * H_ * R_;
        const float* b2 = rb2 + (size_t)(m - 1) * R_;
        int o  = t & 31;
        int bq = t >> 5;                     // 0..7
        #pragma unroll
        for (int i = 0; i < TB / 8; ++i) {
            int bb = bq + i * 8;
            float acc = b2[o];
            for (int j = 0; j < H_; ++j)
                acc = fmaf(hs[bb][j], W2[(size_t)j * R_ + o], acc);
            r_out[((size_t)(m - 1) * B_ + (b0 + bb)) * R_ + o] = acc;
        }
    }
}

// ---------------------------------------------------------------------------
// Kernel 2: per-b fused TPR chain.
//  Phase M: one streaming pass over tpr[b] (512 KB) building
//           M_k[e][f] = sum_r r_k[r] * tpr[b,e,r,f]   for k=0..2   (48 KB LDS)
//  Phase S: wave 0 runs the sequential chain
//           t_k[f] = sum_e x_k[e] * M_k[e][f];  i_k = LN(t_k);  x_{k+1}=i_k
//           out[b] = (i1+i2+i3) @ Z
// grid B, block 256
// ---------------------------------------------------------------------------
__global__ __launch_bounds__(256) void tpr_kernel(
    const float* __restrict__ tpr,   // [B,E,R,E]
    const float* __restrict__ e0,    // [B,E]
    const float* __restrict__ rws,   // [3,B,R]
    const float* __restrict__ ln_g,  // [3,E]
    const float* __restrict__ ln_b,  // [3,E]
    const float* __restrict__ Z,     // [E,L]
    float* __restrict__ out)         // [B,L]
{
    __shared__ __align__(16) float M[3][E_][E_];   // 48 KB
    __shared__ float xcur[E_];
    __shared__ float ssum_sh[E_];
    __shared__ float rsh[3][R_];

    const int t = threadIdx.x;
    const int b = blockIdx.x;

    if (t < 96) { int k = t >> 5, j = t & 31; rsh[k][j] = rws[((size_t)k * B_ + b) * R_ + j]; }
    if (t < E_) xcur[t] = e0[(size_t)b * E_ + t];
    __syncthreads();

    // ---- Phase M: stream tpr[b] once (float4) ----
    const float4* tpr4 = (const float4*)(tpr + (size_t)b * E_ * R_ * E_);
    const int f4 = t & 15;       // which float4 within the 64-f row
    const int eg = t >> 4;       // 0..15

    #pragma unroll
    for (int ep = 0; ep < 4; ++ep) {
        int e = eg + 16 * ep;
        float4 a0 = {0, 0, 0, 0}, a1 = {0, 0, 0, 0}, a2 = {0, 0, 0, 0};
        for (int r = 0; r < R_; ++r) {
            float4 v = tpr4[e * 512 + r * 16 + f4];
            float w0 = rsh[0][r], w1 = rsh[1][r], w2 = rsh[2][r];
            a0.x = fmaf(w0, v.x, a0.x); a0.y = fmaf(w0, v.y, a0.y);
            a0.z = fmaf(w0, v.z, a0.z); a0.w = fmaf(w0, v.w, a0.w);
            a1.x = fmaf(w1, v.x, a1.x); a1.y = fmaf(w1, v.y, a1.y);
            a1.z = fmaf(w1, v.z, a1.z); a1.w = fmaf(w1, v.w, a1.w);
            a2.x = fmaf(w2, v.x, a2.x); a2.y = fmaf(w2, v.y, a2.y);
            a2.z = fmaf(w2, v.z, a2.z); a2.w = fmaf(w2, v.w, a2.w);
        }
        ((float4*)&M[0][e][0])[f4] = a0;
        ((float4*)&M[1][e][0])[f4] = a1;
        ((float4*)&M[2][e][0])[f4] = a2;
    }
    __syncthreads();

    // ---- Phase S: sequential LN chain on wave 0 ----
    float ssum = 0.0f;
    for (int k = 0; k < 3; ++k) {
        float iv = 0.0f;
        if (t < E_) {
            const int f = t;
            float acc = 0.0f;
            for (int e = 0; e < E_; ++e)
                acc = fmaf(xcur[e], M[k][e][f], acc);
            // LayerNorm across the 64 lanes (f dimension)
            float s = acc;
            #pragma unroll
            for (int off = 32; off >= 1; off >>= 1) s += __shfl_xor(s, off, 64);
            float mu = s * (1.0f / 64.0f);
            float d = acc - mu;
            float vs = d * d;
            #pragma unroll
            for (int off = 32; off >= 1; off >>= 1) vs += __shfl_xor(vs, off, 64);
            float var = vs * (1.0f / 64.0f);
            iv = ln_g[k * E_ + f] * d * rsqrtf(var + EPS_) + ln_b[k * E_ + f];
            ssum += iv;
        }
        __syncthreads();
        if (t < E_) xcur[t] = iv;
        __syncthreads();
    }

    if (t < E_) ssum_sh[t] = ssum;
    __syncthreads();

    if (t < L_) {
        float acc = 0.0f;
        for (int f = 0; f < E_; ++f)
            acc = fmaf(ssum_sh[f], Z[f * L_ + t], acc);
        out[(size_t)b * L_ + t] = acc;
    }
}

// ---------------------------------------------------------------------------
extern "C" void kernel_launch(void* const* d_in, const int* in_sizes, int n_in,
                              void* d_out, int out_size, void* d_ws, size_t ws_size,
                              hipStream_t stream) {
    const float* x    = (const float*)d_in[0];
    const float* tpr  = (const float*)d_in[1];
    const float* eW1  = (const float*)d_in[2];
    const float* eb1  = (const float*)d_in[3];
    const float* eW2  = (const float*)d_in[4];
    const float* eb2  = (const float*)d_in[5];
    const float* rW1  = (const float*)d_in[6];
    const float* rb1  = (const float*)d_in[7];
    const float* rW2  = (const float*)d_in[8];
    const float* rb2  = (const float*)d_in[9];
    const float* ln_g = (const float*)d_in[10];
    const float* ln_b = (const float*)d_in[11];
    const float* Z    = (const float*)d_in[12];
    float* out = (float*)d_out;

    float* e0_ws = (float*)d_ws;             // B*E floats
    float* r_ws  = e0_ws + (size_t)B_ * E_;  // 3*B*R floats

    dim3 g1(B_ / TB, 4);
    mlp_kernel<<<g1, 256, 0, stream>>>(x, eW1, eb1, eW2, eb2,
                                       rW1, rb1, rW2, rb2, e0_ws, r_ws);
    tpr_kernel<<<B_, 256, 0, stream>>>(tpr, e0_ws, r_ws, ln_g, ln_b, Z, out);
}